// Round 1
// baseline (121.483 us; speedup 1.0000x reference)
//
#include <hip/hip_runtime.h>

// Problem constants (match reference)
#define Bdim 4
#define Ndim 512
#define Ddim 64
#define DHdim 63
#define HIDdim 64

// Kernel 1: zsum[b][d] = sum_m z[b][m][d].  Grid = B blocks, 256 threads.
__global__ void __launch_bounds__(256) zsum_kernel(const float* __restrict__ z,
                                                   float* __restrict__ zsum) {
    int b = blockIdx.x;
    int tid = threadIdx.x;
    int d = tid & 63;       // feature
    int chunk = tid >> 6;   // 0..3, strided over m
    const float* zb = z + (size_t)b * Ndim * Ddim;
    float acc = 0.f;
    for (int m = chunk; m < Ndim; m += 4) {
        acc += zb[m * Ddim + d];   // lanes d=0..63 consecutive -> coalesced
    }
    __shared__ float part[4][64];
    part[chunk][d] = acc;
    __syncthreads();
    if (chunk == 0) {
        zsum[b * Ddim + d] = part[0][d] + part[1][d] + part[2][d] + part[3][d];
    }
}

// Kernel 2: per (b,n): x = [||z[b,n]||^2 + ||g||^2, h[b,n,:]] (64-dim),
// y = MLP(x), t = sum_o y_o, out[b,n,d] = t * zsum[b,d].
// One wave per (b,n); 4 waves (256 threads) per block; grid = B*N/4 = 512.
__global__ void __launch_bounds__(256) mlp_diag_kernel(
    const float* __restrict__ z, const float* __restrict__ h,
    const float* __restrict__ g,
    const float* __restrict__ W0, const float* __restrict__ b0,
    const float* __restrict__ W1, const float* __restrict__ b1,
    const float* __restrict__ W2, const float* __restrict__ b2,
    const float* __restrict__ W3, const float* __restrict__ b3,
    const float* __restrict__ zsum, float* __restrict__ out)
{
    int tid  = threadIdx.x;
    int wave = tid >> 6;   // 0..3
    int lane = tid & 63;
    int bn = blockIdx.x * 4 + wave;        // 0..2047
    int b  = bn >> 9;                      // /N (N=512)
    int n  = bn & 511;

    // s = ||z[b,n]||^2 + ||g||^2  (wave butterfly reduce)
    float zv = z[((size_t)b * Ndim + n) * Ddim + lane];
    float p = zv * zv;
    if (lane < 3) { float gv = g[lane]; p += gv * gv; }
    #pragma unroll
    for (int off = 32; off; off >>= 1) p += __shfl_xor(p, off, 64);

    // x vector: lane 0 holds s, lanes 1..63 hold h[b,n,0..62]
    float x = (lane == 0) ? p
            : h[((size_t)b * Ndim + n) * DHdim + (lane - 1)];

    __shared__ float xs[4][2][64];   // per-wave ping-pong activation buffers
    int cur = 0;
    xs[wave][cur][lane] = x;
    __syncthreads();

    const float* Ws[4] = {W0, W1, W2, W3};
    const float* bs[4] = {b0, b1, b2, b3};
    #pragma unroll 1
    for (int L = 0; L < 4; ++L) {
        const float* wrow = Ws[L] + lane * 64;  // lane owns output row `lane`
        float acc = bs[L][lane];
        #pragma unroll
        for (int j = 0; j < 64; ++j) {
            acc = fmaf(wrow[j], xs[wave][cur][j], acc);  // xs[..][j] broadcast, no bank conflict
        }
        if (L < 3) acc = fmaxf(acc, 0.f);   // relu on first 3 layers only
        cur ^= 1;
        xs[wave][cur][lane] = acc;
        __syncthreads();
    }

    // t = sum over output features
    float y = xs[wave][cur][lane];
    #pragma unroll
    for (int off = 32; off; off >>= 1) y += __shfl_xor(y, off, 64);

    out[((size_t)b * Ndim + n) * Ddim + lane] = y * zsum[b * Ddim + lane];
}

extern "C" void kernel_launch(void* const* d_in, const int* in_sizes, int n_in,
                              void* d_out, int out_size, void* d_ws, size_t ws_size,
                              hipStream_t stream) {
    const float* z  = (const float*)d_in[0];
    const float* h  = (const float*)d_in[1];
    const float* g  = (const float*)d_in[2];
    const float* W0 = (const float*)d_in[3];
    const float* b0 = (const float*)d_in[4];
    const float* W1 = (const float*)d_in[5];
    const float* b1 = (const float*)d_in[6];
    const float* W2 = (const float*)d_in[7];
    const float* b2 = (const float*)d_in[8];
    const float* W3 = (const float*)d_in[9];
    const float* b3 = (const float*)d_in[10];
    float* out  = (float*)d_out;
    float* zsum = (float*)d_ws;   // B*D floats = 1 KiB

    zsum_kernel<<<Bdim, 256, 0, stream>>>(z, zsum);
    mlp_diag_kernel<<<(Bdim * Ndim) / 4, 256, 0, stream>>>(
        z, h, g, W0, b0, W1, b1, W2, b2, W3, b3, zsum, out);
}

// Round 2
// 78.121 us; speedup vs baseline: 1.5551x; 1.5551x over previous
//
#include <hip/hip_runtime.h>

#define Bdim 4
#define Ndim 512
#define Ddim 64
#define DHdim 63
#define WSTRIDE 68   // LDS floats per weight row: 16B-aligned, spreads bank quads

// One fused kernel. Grid = 256 blocks (1/CU), 256 threads (4 waves).
// Block bid: b = bid>>6, handles n = (bid&63)*8 .. +7 (2 pairs per wave).
// Phase A (per block): stage W0..W2+biases to LDS; reduce zsum[b,:] and
//   cw3[j] = sum_o W3[o][j] (last layer folded analytically since the
//   consumer only needs t = sum_o y_o).
// Phase B (per wave, no block barriers): x in registers (lane j owns x_j),
//   weights from LDS b128 shared across 2 pairs, x broadcast via v_readlane.
__global__ void __launch_bounds__(256) subequi_fused_kernel(
    const float* __restrict__ z, const float* __restrict__ h,
    const float* __restrict__ g,
    const float* __restrict__ W0, const float* __restrict__ b0,
    const float* __restrict__ W1, const float* __restrict__ b1,
    const float* __restrict__ W2, const float* __restrict__ b2,
    const float* __restrict__ W3, const float* __restrict__ b3,
    float* __restrict__ out)
{
    __shared__ float wbuf[3][64 * WSTRIDE];   // 52224 B
    __shared__ float biases[3][64];
    __shared__ float b3s[64];
    __shared__ float cw3[64];
    __shared__ float zsumB[64];
    __shared__ float partZ[16][64];
    __shared__ float partW[16][64];
    // total = 61952 B (< 64 KiB static limit)

    const int tid = threadIdx.x;
    const int bid = blockIdx.x;
    const int b = bid >> 6;
    const int nbase = (bid & 63) * 8;
    const int row = tid >> 4;
    const int dq  = (tid & 15) * 4;

    // ---- Phase A ----
    // zsum partials: flat float4 f = tid + i*256 over z[b] (8192 float4).
    // d of this float4 = (4*f) & 63 = dq (constant per thread).
    const float4* zb4 = (const float4*)(z + (size_t)b * Ndim * Ddim);
    float4 accz = make_float4(0.f, 0.f, 0.f, 0.f);
    #pragma unroll
    for (int i = 0; i < 32; ++i) {
        float4 v = zb4[tid + i * 256];
        accz.x += v.x; accz.y += v.y; accz.z += v.z; accz.w += v.w;
    }
    *(float4*)&partZ[row][dq] = accz;

    // W3 column-sum partials (1024 float4, 4 per thread)
    const float4* w3v = (const float4*)W3;
    float4 accw = make_float4(0.f, 0.f, 0.f, 0.f);
    #pragma unroll
    for (int i = 0; i < 4; ++i) {
        float4 v = w3v[tid + i * 256];
        accw.x += v.x; accw.y += v.y; accw.z += v.z; accw.w += v.w;
    }
    *(float4*)&partW[row][dq] = accw;

    // stage W0..W2 to LDS, stride-68 rows (coalesced global, aligned LDS b128)
    {
        const float* Ws[3] = {W0, W1, W2};
        #pragma unroll
        for (int L = 0; L < 3; ++L) {
            const float4* wv = (const float4*)Ws[L];
            #pragma unroll
            for (int i = 0; i < 4; ++i) {
                int f = tid + i * 256;          // 0..1023
                float4 v = wv[f];
                int o  = f >> 4;                // 16 float4 per 64-float row
                int jb = (f & 15) * 4;
                *(float4*)&wbuf[L][o * WSTRIDE + jb] = v;
            }
        }
        if (tid < 64) {
            biases[0][tid] = b0[tid];
            biases[1][tid] = b1[tid];
            biases[2][tid] = b2[tid];
            b3s[tid] = b3[tid];
        }
    }
    __syncthreads();
    if (tid < 64) {
        float sz = 0.f, sw = 0.f;
        #pragma unroll
        for (int r = 0; r < 16; ++r) { sz += partZ[r][tid]; sw += partW[r][tid]; }
        zsumB[tid] = sz;
        cw3[tid]  = sw;
    }
    __syncthreads();

    // ---- Phase B ----
    const int wave = tid >> 6;
    const int lane = tid & 63;
    const int n0 = nbase + wave * 2;
    const int n1 = n0 + 1;

    const float gg_part = (lane < 3) ? g[lane] * g[lane] : 0.f;
    const float zsv  = zsumB[lane];
    const float cw3v = cw3[lane];
    const float b3v  = b3s[lane];
    const float bv[3] = { biases[0][lane], biases[1][lane], biases[2][lane] };

    // s_p = ||z[b,n_p]||^2 + ||g||^2 via butterfly
    float zv0 = z[((size_t)(b * Ndim + n0)) * Ddim + lane];
    float zv1 = z[((size_t)(b * Ndim + n1)) * Ddim + lane];
    float s0 = fmaf(zv0, zv0, gg_part);
    float s1 = fmaf(zv1, zv1, gg_part);
    #pragma unroll
    for (int off = 32; off; off >>= 1) {
        s0 += __shfl_xor(s0, off, 64);
        s1 += __shfl_xor(s1, off, 64);
    }

    // lane j owns x_j: lane 0 = gram diag, lanes 1..63 = h[b,n,0..62]
    float x0 = (lane == 0) ? s0 : h[((size_t)(b * Ndim + n0)) * DHdim + (lane - 1)];
    float x1 = (lane == 0) ? s1 : h[((size_t)(b * Ndim + n1)) * DHdim + (lane - 1)];

    #pragma unroll
    for (int L = 0; L < 3; ++L) {
        // split accumulators -> 4 independent fma chains across 2 pairs
        float a0a = bv[L], a0b = 0.f, a1a = 0.f, a1b = 0.f;
        const float* wrow = &wbuf[L][lane * WSTRIDE];
        #pragma unroll
        for (int jq = 0; jq < 16; ++jq) {
            float4 w4 = *(const float4*)&wrow[jq * 4];
            #pragma unroll
            for (int k = 0; k < 4; ++k) {
                const int j = jq * 4 + k;
                float wk  = (&w4.x)[k];
                float xb0 = __int_as_float(__builtin_amdgcn_readlane(__float_as_int(x0), j));
                float xb1 = __int_as_float(__builtin_amdgcn_readlane(__float_as_int(x1), j));
                if (k & 1) { a0b = fmaf(wk, xb0, a0b); a1b = fmaf(wk, xb1, a1b); }
                else       { a0a = fmaf(wk, xb0, a0a); a1a = fmaf(wk, xb1, a1a); }
            }
        }
        x0 = fmaxf(a0a + a0b, 0.f);
        x1 = fmaf(1.f, 0.f, fmaxf(a1a + a1b + bv[L], 0.f));  // bias for pair 1
    }

    // folded last layer: t_p = sum_lanes( cw3[lane]*x_p + b3[lane] )
    float t0 = fmaf(cw3v, x0, b3v);
    float t1 = fmaf(cw3v, x1, b3v);
    #pragma unroll
    for (int off = 32; off; off >>= 1) {
        t0 += __shfl_xor(t0, off, 64);
        t1 += __shfl_xor(t1, off, 64);
    }

    out[((size_t)(b * Ndim + n0)) * Ddim + lane] = t0 * zsv;
    out[((size_t)(b * Ndim + n1)) * Ddim + lane] = t1 * zsv;
}

extern "C" void kernel_launch(void* const* d_in, const int* in_sizes, int n_in,
                              void* d_out, int out_size, void* d_ws, size_t ws_size,
                              hipStream_t stream) {
    const float* z  = (const float*)d_in[0];
    const float* h  = (const float*)d_in[1];
    const float* g  = (const float*)d_in[2];
    const float* W0 = (const float*)d_in[3];
    const float* b0 = (const float*)d_in[4];
    const float* W1 = (const float*)d_in[5];
    const float* b1 = (const float*)d_in[6];
    const float* W2 = (const float*)d_in[7];
    const float* b2 = (const float*)d_in[8];
    const float* W3 = (const float*)d_in[9];
    const float* b3 = (const float*)d_in[10];
    float* out = (float*)d_out;

    subequi_fused_kernel<<<256, 256, 0, stream>>>(
        z, h, g, W0, b0, W1, b1, W2, b2, W3, b3, out);
}

// Round 3
// 77.643 us; speedup vs baseline: 1.5646x; 1.0062x over previous
//
#include <hip/hip_runtime.h>

#define Bdim 4
#define Ndim 512
#define Ddim 64
#define DHdim 63
#define WSTRIDE 68   // LDS floats per weight row: 16B-aligned, spreads bank quads

// One fused kernel. Grid = 256 blocks (1/CU), 256 threads (4 waves).
// Block bid: b = bid>>6, handles n = (bid&63)*8 .. +7 (2 pairs per wave).
// out[b,n,d] = t[b,n] * zsum[b,d], where t = sum_o MLP(x)_o and
// x = [||z[b,n]||^2 + ||g||^2, h[b,n,:]]. Last linear folded to cw3/b3 sums.
__global__ void __launch_bounds__(256) subequi_fused_kernel(
    const float* __restrict__ z, const float* __restrict__ h,
    const float* __restrict__ g,
    const float* __restrict__ W0, const float* __restrict__ b0,
    const float* __restrict__ W1, const float* __restrict__ b1,
    const float* __restrict__ W2, const float* __restrict__ b2,
    const float* __restrict__ W3, const float* __restrict__ b3,
    float* __restrict__ out)
{
    __shared__ float wbuf[3][64 * WSTRIDE];   // 52224 B
    __shared__ float biases[3][64];
    __shared__ float b3s[64];
    __shared__ float cw3[64];
    __shared__ float zsumB[64];
    __shared__ float partZ[4][64];            // per-wave partials (shfl-reduced)
    __shared__ float partW[4][64];
    // total ~55.8 KB

    const int tid = threadIdx.x;
    const int bid = blockIdx.x;
    const int b = bid >> 6;
    const int nbase = (bid & 63) * 8;
    const int wave = tid >> 6;
    const int lane = tid & 63;
    const int dq = (tid & 15) * 4;            // float4-aligned d offset

    const int n0 = nbase + wave * 2;
    const int n1 = n0 + 1;

    // ---- early loads (latency hidden under Phase A streaming) ----
    const float zv0 = z[((size_t)(b * Ndim + n0)) * Ddim + lane];
    const float zv1 = z[((size_t)(b * Ndim + n1)) * Ddim + lane];
    const float hv0 = (lane > 0) ? h[((size_t)(b * Ndim + n0)) * DHdim + (lane - 1)] : 0.f;
    const float hv1 = (lane > 0) ? h[((size_t)(b * Ndim + n1)) * DHdim + (lane - 1)] : 0.f;
    const float gg = g[0] * g[0] + g[1] * g[1] + g[2] * g[2];  // uniform scalar loads

    // ---- Phase A ----
    // zsum partials: flat float4 f = tid + i*256 over z[b]; d-of-f = dq (const).
    const float4* zb4 = (const float4*)(z + (size_t)b * Ndim * Ddim);
    float4 accz = make_float4(0.f, 0.f, 0.f, 0.f);
    #pragma unroll
    for (int i = 0; i < 32; ++i) {
        float4 v = zb4[tid + i * 256];
        accz.x += v.x; accz.y += v.y; accz.z += v.z; accz.w += v.w;
    }
    // W3 column-sum partials
    const float4* w3v = (const float4*)W3;
    float4 accw = make_float4(0.f, 0.f, 0.f, 0.f);
    #pragma unroll
    for (int i = 0; i < 4; ++i) {
        float4 v = w3v[tid + i * 256];
        accw.x += v.x; accw.y += v.y; accw.z += v.z; accw.w += v.w;
    }
    // intra-wave reduce across the 4 lanes sharing dq (lane ^16, ^32)
    #pragma unroll
    for (int off = 16; off <= 32; off <<= 1) {
        accz.x += __shfl_xor(accz.x, off, 64);
        accz.y += __shfl_xor(accz.y, off, 64);
        accz.z += __shfl_xor(accz.z, off, 64);
        accz.w += __shfl_xor(accz.w, off, 64);
        accw.x += __shfl_xor(accw.x, off, 64);
        accw.y += __shfl_xor(accw.y, off, 64);
        accw.z += __shfl_xor(accw.z, off, 64);
        accw.w += __shfl_xor(accw.w, off, 64);
    }
    if (lane < 16) {
        *(float4*)&partZ[wave][dq] = accz;
        *(float4*)&partW[wave][dq] = accw;
    }

    // stage W0..W2 to LDS, stride-68 rows (coalesced global, aligned LDS b128)
    {
        const float* Ws[3] = {W0, W1, W2};
        #pragma unroll
        for (int L = 0; L < 3; ++L) {
            const float4* wv = (const float4*)Ws[L];
            #pragma unroll
            for (int i = 0; i < 4; ++i) {
                int f = tid + i * 256;          // 0..1023
                float4 v = wv[f];
                int o  = f >> 4;
                int jb = (f & 15) * 4;
                *(float4*)&wbuf[L][o * WSTRIDE + jb] = v;
            }
        }
        if (tid < 64) {
            biases[0][tid] = b0[tid];
            biases[1][tid] = b1[tid];
            biases[2][tid] = b2[tid];
            b3s[tid] = b3[tid];
        }
    }
    __syncthreads();
    if (tid < 64) {
        zsumB[tid] = partZ[0][tid] + partZ[1][tid] + partZ[2][tid] + partZ[3][tid];
        cw3[tid]   = partW[0][tid] + partW[1][tid] + partW[2][tid] + partW[3][tid];
    }
    __syncthreads();

    // ---- Phase B ----
    const float zsv  = zsumB[lane];
    const float cw3v = cw3[lane];
    const float b3v  = b3s[lane];
    const float bv[3] = { biases[0][lane], biases[1][lane], biases[2][lane] };

    // s_p = ||z[b,n_p]||^2 (butterfly), + ||g||^2 added once after reduce
    float s0 = zv0 * zv0;
    float s1 = zv1 * zv1;
    #pragma unroll
    for (int off = 32; off; off >>= 1) {
        s0 += __shfl_xor(s0, off, 64);
        s1 += __shfl_xor(s1, off, 64);
    }
    s0 += gg;
    s1 += gg;

    // lane j owns x_j: lane 0 = gram diag, lanes 1..63 = h[b,n,0..62]
    float x0 = (lane == 0) ? s0 : hv0;
    float x1 = (lane == 0) ? s1 : hv1;

    #pragma unroll
    for (int L = 0; L < 3; ++L) {
        float a0a = bv[L], a0b = 0.f, a1a = bv[L], a1b = 0.f;
        const float* wrow = &wbuf[L][lane * WSTRIDE];
        #pragma unroll
        for (int jq = 0; jq < 16; ++jq) {
            float4 w4 = *(const float4*)&wrow[jq * 4];
            #pragma unroll
            for (int k = 0; k < 4; ++k) {
                const int j = jq * 4 + k;
                float wk  = (&w4.x)[k];
                float xb0 = __int_as_float(__builtin_amdgcn_readlane(__float_as_int(x0), j));
                float xb1 = __int_as_float(__builtin_amdgcn_readlane(__float_as_int(x1), j));
                if (k & 1) { a0b = fmaf(wk, xb0, a0b); a1b = fmaf(wk, xb1, a1b); }
                else       { a0a = fmaf(wk, xb0, a0a); a1a = fmaf(wk, xb1, a1a); }
            }
        }
        x0 = fmaxf(a0a + a0b, 0.f);
        x1 = fmaxf(a1a + a1b, 0.f);
    }

    // folded last layer: t_p = sum_lanes( cw3[lane]*x_p + b3[lane] )
    float t0 = fmaf(cw3v, x0, b3v);
    float t1 = fmaf(cw3v, x1, b3v);
    #pragma unroll
    for (int off = 32; off; off >>= 1) {
        t0 += __shfl_xor(t0, off, 64);
        t1 += __shfl_xor(t1, off, 64);
    }

    out[((size_t)(b * Ndim + n0)) * Ddim + lane] = t0 * zsv;
    out[((size_t)(b * Ndim + n1)) * Ddim + lane] = t1 * zsv;
}

extern "C" void kernel_launch(void* const* d_in, const int* in_sizes, int n_in,
                              void* d_out, int out_size, void* d_ws, size_t ws_size,
                              hipStream_t stream) {
    const float* z  = (const float*)d_in[0];
    const float* h  = (const float*)d_in[1];
    const float* g  = (const float*)d_in[2];
    const float* W0 = (const float*)d_in[3];
    const float* b0 = (const float*)d_in[4];
    const float* W1 = (const float*)d_in[5];
    const float* b1 = (const float*)d_in[6];
    const float* W2 = (const float*)d_in[7];
    const float* b2 = (const float*)d_in[8];
    const float* W3 = (const float*)d_in[9];
    const float* b3 = (const float*)d_in[10];
    float* out = (float*)d_out;

    subequi_fused_kernel<<<256, 256, 0, stream>>>(
        z, h, g, W0, b0, W1, b1, W2, b2, W3, b3, out);
}